// Round 8
// baseline (681.611 us; speedup 1.0000x reference)
//
#include <hip/hip_runtime.h>

typedef unsigned short ushort_t;
typedef unsigned int uint_t;
typedef __bf16 bf16x8 __attribute__((ext_vector_type(8)));
typedef float f32x4 __attribute__((ext_vector_type(4)));

#define B_ROWS 65536

// Tile geometry: one MFMA tile = 16 rows x 32 k of bf16 = 1024 B = 512 ushorts.
// Unit l (0..63) within a tile <-> (row = l&15, k = (l>>4)*8 .. +8).
#define KT1 12    // K1 k-iters  (K 376 -> 384)
#define NT1 30    // K1 n-tiles  (N 400 -> 480)
#define KTC1 15   // h1' k-tiles (480/32)
#define KI2 13    // K2 k-iters  (K 400 -> 416; h1' cols 400..480 are exact 0)
#define NT2 20    // K2 n-tiles  (N 320)
#define KTC2 10   // h2' k-tiles (320/32)
#define KI3 10    // K3 k-iters  (320/32)
#define NT3 52    // K3 n-tiles  (N 832: aligned head layout + 2 pad tiles for 8-wave split)
#define KTH 25    // heads row-stride in ktiles in LDS (800/32; cols >=800 masked off)

// Aligned head layout (all slots on 8-col boundaries; pads are exact zeros):
//  [0:24)  mu (17 real)   groups 0..2
//  [24:48) lv (17 real)   groups 3..5
//  [48:64) b  (15 real)   groups 6..7
//  [64+48k : +24)  u_k (17 real)  groups 8+6k .. +2
//  [64+48k+24 : +48) w_k (17 real) groups 11+6k .. +2
//  cols [784, 832) pad zeros

#define SZ1 (NT1 * KT1 * 512)
#define SZ2 (NT2 * KI2 * 512)
#define SZ3 (NT3 * KI3 * 512)

// workspace (ushort units): [h2'][h1'][weights]
#define H2_US ((size_t)4096 * KTC2 * 512)
#define H1_US ((size_t)4096 * KTC1 * 512)

__device__ inline ushort_t f2bf(float f) {
    uint_t u = __float_as_uint(f);
    return (ushort_t)((u + 0x7FFFu + ((u >> 16) & 1u)) >> 16);
}
__device__ inline uint_t pack2(float a, float b) {
    return (uint_t)f2bf(a) | ((uint_t)f2bf(b) << 16);
}
__device__ inline float fast_tanh(float x) {
    float e = __expf(2.f * x);
    return 1.f - 2.f / (e + 1.f);
}
__device__ inline void unpack8(uint4 v, float* dst) {
    uint_t q[4] = {v.x, v.y, v.z, v.w};
    #pragma unroll
    for (int m = 0; m < 4; ++m) {
        dst[2 * m]     = __uint_as_float(q[m] << 16);          // low bf16
        dst[2 * m + 1] = __uint_as_float(q[m] & 0xFFFF0000u);  // high bf16
    }
}

// ---------------------------------------------------------------------------
// pack_kernel: fp32 weights -> MFMA-tile-order bf16 + zero-padded fp32 biases.
// ---------------------------------------------------------------------------
__global__ void pack_kernel(const float* __restrict__ W1, const float* __restrict__ W2,
                            const float* __restrict__ Wmu, const float* __restrict__ Wlv,
                            const float* __restrict__ Wu, const float* __restrict__ Ww,
                            const float* __restrict__ Wb,
                            const float* __restrict__ b1, const float* __restrict__ b2,
                            const float* __restrict__ bmu, const float* __restrict__ blv,
                            const float* __restrict__ bu, const float* __restrict__ bw,
                            const float* __restrict__ bb,
                            ushort_t* __restrict__ W1t, ushort_t* __restrict__ W2t,
                            ushort_t* __restrict__ Wht,
                            float* __restrict__ b1p, float* __restrict__ b2p,
                            float* __restrict__ bHp)
{
    int i = blockIdx.x * 256 + threadIdx.x;
    if (i < SZ1) {
        int t = i >> 9, pos = i & 511;
        int l = pos >> 3, j = pos & 7;
        int n = (t / KT1) * 16 + (l & 15);
        int k = (t % KT1) * 32 + (l >> 4) * 8 + j;
        W1t[i] = (n < 400 && k < 376) ? f2bf(W1[k * 400 + n]) : (ushort_t)0;
    } else if (i < SZ1 + SZ2) {
        int i2 = i - SZ1;
        int t = i2 >> 9, pos = i2 & 511;
        int l = pos >> 3, j = pos & 7;
        int n = (t / KI2) * 16 + (l & 15);
        int k = (t % KI2) * 32 + (l >> 4) * 8 + j;
        W2t[i2] = (n < 300 && k < 400) ? f2bf(W2[k * 300 + n]) : (ushort_t)0;
    } else if (i < SZ1 + SZ2 + SZ3) {
        int i3 = i - SZ1 - SZ2;
        int t = i3 >> 9, pos = i3 & 511;
        int l = pos >> 3, j = pos & 7;
        int n = (t / KI3) * 16 + (l & 15);
        int k = (t % KI3) * 32 + (l >> 4) * 8 + j;
        float v = 0.f;
        if (k < 300) {
            if (n < 24)      { if (n < 17) v = Wmu[k * 17 + n]; }
            else if (n < 48) { int c = n - 24; if (c < 17) v = Wlv[k * 17 + c]; }
            else if (n < 64) { int c = n - 48; if (c < 15) v = Wb[k * 15 + c]; }
            else if (n < 784) {
                int r = n - 64, slot = r / 48, c = r % 48;
                if (c < 24) { if (c < 17) v = Wu[k * 255 + slot * 17 + c]; }
                else        { int c2 = c - 24; if (c2 < 17) v = Ww[k * 255 + slot * 17 + c2]; }
            }
        }
        Wht[i3] = f2bf(v);
    } else {
        int j = i - SZ1 - SZ2 - SZ3;
        if (j < 480) {
            b1p[j] = (j < 400) ? b1[j] : 0.f;
        } else if (j < 800) {
            int n = j - 480;
            b2p[n] = (n < 300) ? b2[n] : 0.f;
        } else if (j < 1632) {
            int n = j - 800;
            float v = 0.f;
            if (n < 24)      { if (n < 17) v = bmu[n]; }
            else if (n < 48) { int c = n - 24; if (c < 17) v = blv[c]; }
            else if (n < 64) { int c = n - 48; if (c < 15) v = bb[c]; }
            else if (n < 784) {
                int r = n - 64, slot = r / 48, c = r % 48;
                if (c < 24) { if (c < 17) v = bu[slot * 17 + c]; }
                else        { int c2 = c - 24; if (c2 < 17) v = bw[slot * 17 + c2]; }
            }
            bHp[n] = v;
        }
    }
}

// ---------------------------------------------------------------------------
// gemm_nb: barrier-free, LDS-free GEMM. C' = act(A @ B^T + bias).
//   B-frags read per-lane DIRECTLY from global (weights are L2-resident and
//   shared by all blocks; 16B/lane x 64 = 1KB coalesced per tile).
//   A-frags per-lane from global (CVT_A: f32 x row-major -> bf16 in-reg).
// 256 thr = 4 waves. BM=128, BN=160. Wave (mh=wv>>1, nh=wv&1) owns
// rowtiles [4mh,4mh+4) x ntiles [5nh,5nh+5): acc[4][5]=80 VGPR,
// 9 loads : 20 MFMA per kt. Zero barriers, zero LDS -> the k-loop is a pure
// unrolled load/MFMA dataflow the compiler pipelines deeply (flow-v3 pattern).
// __launch_bounds__(256,4) -> <=128 VGPR -> 4 blocks/CU.
// XCD-bijective remap keeps the NX n-blocks of one rowblock on one XCD.
// ---------------------------------------------------------------------------
template<int KITERS, int NX, bool RELU, bool CVT_A>
__global__ __launch_bounds__(256, 4)
void gemm_nb(const ushort_t* __restrict__ At, const float* __restrict__ xf,
             const ushort_t* __restrict__ Bt, const float* __restrict__ bias,
             ushort_t* __restrict__ C, int kTA, int kTC)
{
    const int tid = threadIdx.x;
    const int lane = tid & 63, wv = tid >> 6;
    const int mh = wv >> 1, nh = wv & 1;
    const int q = lane >> 4, l16 = lane & 15;

    // bijective XCD remap (gridDim.x = NX*512; 512 % 8 == 0)
    const int b = blockIdx.x;
    const int xcd = b & 7, idx = b >> 3;
    const int grp = idx / NX;
    const int bx = idx - grp * NX;
    const int by = xcd + grp * 8;
    const int nb0 = bx * 10;
    const int rowblk0 = by * 8;

    f32x4 acc[4][5];
    #pragma unroll
    for (int r = 0; r < 4; ++r)
        #pragma unroll
        for (int c = 0; c < 5; ++c)
            acc[r][c] = (f32x4){0.f, 0.f, 0.f, 0.f};

    #pragma unroll
    for (int kt = 0; kt < KITERS; ++kt) {
        // A-frags: 4 rowtiles, per-lane direct
        bf16x8 a[4];
        #pragma unroll
        for (int r = 0; r < 4; ++r) {
            int rt = rowblk0 + mh * 4 + r;
            if (CVT_A) {
                int row = rt * 16 + l16;
                int k0 = kt * 32 + q * 8;
                uint4 o = {0u, 0u, 0u, 0u};
                if (k0 + 8 <= 376) {
                    const float4* p = reinterpret_cast<const float4*>(
                        xf + (size_t)row * 376 + k0);
                    float4 v0 = p[0], v1 = p[1];
                    o.x = pack2(v0.x, v0.y); o.y = pack2(v0.z, v0.w);
                    o.z = pack2(v1.x, v1.y); o.w = pack2(v1.z, v1.w);
                }
                a[r] = __builtin_bit_cast(bf16x8, o);
            } else {
                a[r] = __builtin_bit_cast(bf16x8, *reinterpret_cast<const uint4*>(
                    At + (((size_t)rt * kTA + kt) << 9) + lane * 8));
            }
        }
        // B-frags: 5 ntiles, per-lane direct from L2-resident weights
        bf16x8 bfr[5];
        #pragma unroll
        for (int c = 0; c < 5; ++c)
            bfr[c] = __builtin_bit_cast(bf16x8, *reinterpret_cast<const uint4*>(
                Bt + (((size_t)(nb0 + nh * 5 + c) * KITERS + kt) << 9) + lane * 8));
        // 20 MFMA
        #pragma unroll
        for (int r = 0; r < 4; ++r)
            #pragma unroll
            for (int c = 0; c < 5; ++c)
                acc[r][c] = __builtin_amdgcn_mfma_f32_16x16x32_bf16(
                    a[r], bfr[c], acc[r][c], 0, 0, 0);
    }

    // ---- epilogue: bias + act -> tiled C; C/D frag: col=l16, row=q*4+reg ----
    #pragma unroll
    for (int r = 0; r < 4; ++r) {
        int rowblk = rowblk0 + mh * 4 + r;
        #pragma unroll
        for (int c = 0; c < 5; ++c) {
            int n = (nb0 + nh * 5 + c) * 16 + l16;
            float bv = bias[n];
            #pragma unroll
            for (int reg = 0; reg < 4; ++reg) {
                float v = acc[r][c][reg] + bv;
                if (RELU) v = fmaxf(v, 0.f);
                int mrow = q * 4 + reg;
                size_t off = (((size_t)rowblk * kTC + (n >> 5)) << 9)
                           + (size_t)(((n >> 3) & 3) * 16 + mrow) * 8 + (n & 7);
                C[off] = f2bf(v);
            }
        }
    }
}

// ---------------------------------------------------------------------------
// gemm_flow2: K3 + planar flow fused, barrier-free GEMM phase.
//   heads(64x800) = h2'(64x320) @ Wh^T + bH. N padded to 832 (52 ntiles) so
//   8 waves split as (wm=wv>>2 -> rowtiles {2wm,2wm+1}, wn=wv&3 -> 13 ntiles).
//   A and B per-lane from global (no LDS, no barriers in the k-loop);
//   acc[2][13]=104 VGPR. Epilogue writes heads to LDS (tiled, cols<800),
//   ONE barrier, then the proven 4-lane flow from LDS.
// LDS = Hd 100 KB only -> 1 block/CU, 8 waves. launch_bounds(512,2) (<=256 VGPR).
// ---------------------------------------------------------------------------
__global__ __launch_bounds__(512, 2)
void gemm_flow2(const ushort_t* __restrict__ At, const ushort_t* __restrict__ Bt,
                const float* __restrict__ bias, const float* __restrict__ eps,
                float* __restrict__ out)
{
    __shared__ ushort_t Hd[100 * 512];     // 100 KB: heads for 64 rows, tiled
    const int tid = threadIdx.x;
    const int lane = tid & 63, wv = tid >> 6;
    const int wm = wv >> 2, wn = wv & 3;
    const int q = lane >> 4, l16 = lane & 15;
    const long row0 = (long)blockIdx.x * 64;

    f32x4 acc[2][13];
    #pragma unroll
    for (int r = 0; r < 2; ++r)
        #pragma unroll
        for (int c = 0; c < 13; ++c)
            acc[r][c] = (f32x4){0.f, 0.f, 0.f, 0.f};

    #pragma unroll
    for (int kt = 0; kt < KI3; ++kt) {
        bf16x8 a[2];
        #pragma unroll
        for (int r = 0; r < 2; ++r) {
            size_t rtg = (size_t)blockIdx.x * 4 + wm * 2 + r;
            a[r] = __builtin_bit_cast(bf16x8, *reinterpret_cast<const uint4*>(
                At + ((rtg * KTC2 + kt) << 9) + lane * 8));
        }
        #pragma unroll
        for (int c = 0; c < 13; ++c) {
            bf16x8 bb = __builtin_bit_cast(bf16x8, *reinterpret_cast<const uint4*>(
                Bt + (((size_t)(wn * 13 + c) * KI3 + kt) << 9) + lane * 8));
            acc[0][c] = __builtin_amdgcn_mfma_f32_16x16x32_bf16(a[0], bb, acc[0][c], 0, 0, 0);
            acc[1][c] = __builtin_amdgcn_mfma_f32_16x16x32_bf16(a[1], bb, acc[1][c], 0, 0, 0);
        }
    }

    // ---- epilogue: bias -> heads in LDS (tiled, cols < 800 only) ----
    #pragma unroll
    for (int r = 0; r < 2; ++r) {
        int rts = wm * 2 + r;
        #pragma unroll
        for (int c = 0; c < 13; ++c) {
            int nt = wn * 13 + c;
            if (nt < 50) {                      // wave-uniform per (wn,c)
                int n = nt * 16 + l16;
                float bv = bias[n];
                #pragma unroll
                for (int reg = 0; reg < 4; ++reg) {
                    int r16 = q * 4 + reg;
                    Hd[((rts * KTH + (n >> 5)) << 9) + (((n >> 3) & 3) << 7)
                       + (r16 << 3) + (n & 7)] = f2bf(acc[r][c][reg] + bv);
                }
            }
        }
    }
    __syncthreads();

    // ---- flow phase: threads 0..255 = 64 rows x 4 lanes, heads from LDS ----
    if (tid < 256) {
        const int sub = tid & 3;
        const int row = tid >> 2;
        const ushort_t* hb = &Hd[(((row >> 4) * KTH) << 9) + ((row & 15) << 3)];
        const long grow = row0 + row;

        auto ldg8 = [&](int g, float* dst) {
            uint4 v = *reinterpret_cast<const uint4*>(
                hb + ((g >> 2) << 9) + ((g & 3) << 7));
            unpack8(v, dst);
        };

        float z[8];
        float lp = 0.f;
        {
            float amu[8] = {0,0,0,0,0,0,0,0}, alv[8] = {0,0,0,0,0,0,0,0};
            if (sub < 3) {
                ldg8(sub, amu);
                ldg8(3 + sub, alv);
            }
            float ep[8];
            #pragma unroll
            for (int c = 0; c < 8; ++c) {
                int i = sub * 8 + c;
                ep[c] = (i < 17) ? eps[grow * 17 + i] : 0.f;
            }
            #pragma unroll
            for (int c = 0; c < 8; ++c) {
                float mu = fast_tanh(amu[c]);
                float lv = fast_tanh(alv[c]);
                z[c] = mu + __expf(lv) * ep[c];
                int i = sub * 8 + c;
                lp += (i < 17) ? (-0.5f * ep[c] * ep[c] - lv - 0.918938533f) : 0.f;
            }
        }

        float bv[16];
        ldg8(6, &bv[0]);
        ldg8(7, &bv[8]);

        float ldj = 0.f;
        #pragma unroll
        for (int k = 0; k < 15; ++k) {
            float au[8] = {0,0,0,0,0,0,0,0}, aw[8] = {0,0,0,0,0,0,0,0};
            if (sub < 3) {
                ldg8(8 + 6 * k + sub, au);
                ldg8(11 + 6 * k + sub, aw);
            }
            float uw = 0.f, w2 = 0.f, wz = 0.f;
            #pragma unroll
            for (int c = 0; c < 8; ++c) {
                uw += aw[c] * au[c];
                w2 += aw[c] * aw[c];
                wz += aw[c] * z[c];
            }
            uw += __shfl_xor(uw, 1); uw += __shfl_xor(uw, 2);
            w2 += __shfl_xor(w2, 1); w2 += __shfl_xor(w2, 2);
            wz += __shfl_xor(wz, 1); wz += __shfl_xor(wz, 2);

            float sp = (uw > 15.f) ? uw : __logf(1.f + __expf(uw));
            float m = sp - 1.f;                          // -1 + softplus(w.u)
            float coef = (m - uw) / fmaxf(w2, 1e-20f);
            float t = fast_tanh(wz + bv[k]);
            #pragma unroll
            for (int c = 0; c < 8; ++c)
                z[c] += (au[c] + coef * aw[c]) * t;
            float psi = m * (1.f - t * t);               // psi^T u_hat == m analytically
            ldj += __logf(fmaxf(fabsf(1.f + psi), 1e-30f));
        }

        lp += __shfl_xor(lp, 1); lp += __shfl_xor(lp, 2);
        #pragma unroll
        for (int c = 0; c < 8; ++c) {
            int i = sub * 8 + c;
            if (i < 17) out[grow * 17 + i] = z[c];
        }
        float lpf = lp - ldj;
        if (sub == 0) {
            out[(long)B_ROWS * 17 + grow] = __expf(lpf);
            out[(long)B_ROWS * 18 + grow] = lpf;
        }
    }
}

// ---------------------------------------------------------------------------
extern "C" void kernel_launch(void* const* d_in, const int* in_sizes, int n_in,
                              void* d_out, int out_size, void* d_ws, size_t ws_size,
                              hipStream_t stream)
{
    const float* x   = (const float*)d_in[0];
    const float* eps = (const float*)d_in[1];
    float* out = (float*)d_out;

    // ws layout (ushort units): [h2'][h1'][weights + biases]
    ushort_t* ws = (ushort_t*)d_ws;
    ushort_t* R_h2 = ws;
    ushort_t* R_h1 = ws + H2_US;
    ushort_t* W1t = ws + H2_US + H1_US;
    ushort_t* W2t = W1t + SZ1;
    ushort_t* Wht = W2t + SZ2;
    float* b1p = (float*)(Wht + SZ3);
    float* b2p = b1p + 480;
    float* bHp = b2p + 320;

    const int packN = SZ1 + SZ2 + SZ3 + 1632;
    pack_kernel<<<(packN + 255) / 256, 256, 0, stream>>>(
        (const float*)d_in[2],  (const float*)d_in[4],
        (const float*)d_in[6],  (const float*)d_in[8],
        (const float*)d_in[10], (const float*)d_in[12], (const float*)d_in[14],
        (const float*)d_in[3],  (const float*)d_in[5],
        (const float*)d_in[7],  (const float*)d_in[9],
        (const float*)d_in[11], (const float*)d_in[13], (const float*)d_in[15],
        W1t, W2t, Wht, b1p, b2p, bHp);

    // K1: h1' = relu(x @ W1^T + b1), cvt fused.  M=65536 K=384 N=480
    gemm_nb<KT1, 3, true, true><<<3 * 512, 256, 0, stream>>>(
        nullptr, x, W1t, b1p, R_h1, 0, KTC1);
    // K2: h2' = relu(h1' @ W2^T + b2).           M=65536 K=416 N=320
    gemm_nb<KI2, 2, true, false><<<2 * 512, 256, 0, stream>>>(
        R_h1, nullptr, W2t, b2p, R_h2, KTC1, KTC2);
    // K3+K4 fused: heads (LDS-resident) + planar flow + log-prob
    gemm_flow2<<<B_ROWS / 64, 512, 0, stream>>>(R_h2, Wht, bHp, eps, out);
}

// Round 9
// 421.787 us; speedup vs baseline: 1.6160x; 1.6160x over previous
//
#include <hip/hip_runtime.h>

typedef unsigned short ushort_t;
typedef unsigned int uint_t;
typedef __bf16 bf16x8 __attribute__((ext_vector_type(8)));
typedef float f32x4 __attribute__((ext_vector_type(4)));

#define B_ROWS 65536

// Tile geometry: one MFMA tile = 16 rows x 32 k of bf16 = 1024 B = 512 ushorts.
// Unit l (0..63) within a tile <-> (row = l&15, k = (l>>4)*8 .. +8).
#define KT1 12    // K1 k-iters  (K 376 -> 384)
#define NT1 30    // K1 n-tiles  (N 400 -> 480)
#define KTC1 15   // h1' k-tiles (480/32)
#define KI2 13    // K2 k-iters  (K 400 -> 416; h1' cols 400..480 are exact 0)
#define NT2 20    // K2 n-tiles  (N 320)
#define KTC2 10   // h2' k-tiles (320/32)
#define KI3 10    // K3 k-iters  (320/32)
#define NT3 52    // K3 n-tiles  (N 832: aligned head layout + 2 pad tiles for 8-wave split)
#define KTH 25    // heads row-stride in ktiles in LDS (800/32; cols >=800 masked off)

// Aligned head layout (all slots on 8-col boundaries; pads are exact zeros):
//  [0:24)  mu (17 real)   groups 0..2
//  [24:48) lv (17 real)   groups 3..5
//  [48:64) b  (15 real)   groups 6..7
//  [64+48k : +24)  u_k (17 real)  groups 8+6k .. +2
//  [64+48k+24 : +48) w_k (17 real) groups 11+6k .. +2
//  cols [784, 832) pad zeros

#define SZ1 (NT1 * KT1 * 512)
#define SZ2 (NT2 * KI2 * 512)
#define SZ3 (NT3 * KI3 * 512)

// workspace (ushort units): [h2'][h1'][weights]
#define H2_US ((size_t)4096 * KTC2 * 512)
#define H1_US ((size_t)4096 * KTC1 * 512)

__device__ inline ushort_t f2bf(float f) {
    uint_t u = __float_as_uint(f);
    return (ushort_t)((u + 0x7FFFu + ((u >> 16) & 1u)) >> 16);
}
__device__ inline uint_t pack2(float a, float b) {
    return (uint_t)f2bf(a) | ((uint_t)f2bf(b) << 16);
}
__device__ inline float fast_tanh(float x) {
    float e = __expf(2.f * x);
    return 1.f - 2.f / (e + 1.f);
}
__device__ inline void unpack8(uint4 v, float* dst) {
    uint_t q[4] = {v.x, v.y, v.z, v.w};
    #pragma unroll
    for (int m = 0; m < 4; ++m) {
        dst[2 * m]     = __uint_as_float(q[m] << 16);          // low bf16
        dst[2 * m + 1] = __uint_as_float(q[m] & 0xFFFF0000u);  // high bf16
    }
}

// ---------------------------------------------------------------------------
// pack_kernel: fp32 weights -> MFMA-tile-order bf16 + zero-padded fp32 biases.
// ---------------------------------------------------------------------------
__global__ void pack_kernel(const float* __restrict__ W1, const float* __restrict__ W2,
                            const float* __restrict__ Wmu, const float* __restrict__ Wlv,
                            const float* __restrict__ Wu, const float* __restrict__ Ww,
                            const float* __restrict__ Wb,
                            const float* __restrict__ b1, const float* __restrict__ b2,
                            const float* __restrict__ bmu, const float* __restrict__ blv,
                            const float* __restrict__ bu, const float* __restrict__ bw,
                            const float* __restrict__ bb,
                            ushort_t* __restrict__ W1t, ushort_t* __restrict__ W2t,
                            ushort_t* __restrict__ Wht,
                            float* __restrict__ b1p, float* __restrict__ b2p,
                            float* __restrict__ bHp)
{
    int i = blockIdx.x * 256 + threadIdx.x;
    if (i < SZ1) {
        int t = i >> 9, pos = i & 511;
        int l = pos >> 3, j = pos & 7;
        int n = (t / KT1) * 16 + (l & 15);
        int k = (t % KT1) * 32 + (l >> 4) * 8 + j;
        W1t[i] = (n < 400 && k < 376) ? f2bf(W1[k * 400 + n]) : (ushort_t)0;
    } else if (i < SZ1 + SZ2) {
        int i2 = i - SZ1;
        int t = i2 >> 9, pos = i2 & 511;
        int l = pos >> 3, j = pos & 7;
        int n = (t / KI2) * 16 + (l & 15);
        int k = (t % KI2) * 32 + (l >> 4) * 8 + j;
        W2t[i2] = (n < 300 && k < 400) ? f2bf(W2[k * 300 + n]) : (ushort_t)0;
    } else if (i < SZ1 + SZ2 + SZ3) {
        int i3 = i - SZ1 - SZ2;
        int t = i3 >> 9, pos = i3 & 511;
        int l = pos >> 3, j = pos & 7;
        int n = (t / KI3) * 16 + (l & 15);
        int k = (t % KI3) * 32 + (l >> 4) * 8 + j;
        float v = 0.f;
        if (k < 300) {
            if (n < 24)      { if (n < 17) v = Wmu[k * 17 + n]; }
            else if (n < 48) { int c = n - 24; if (c < 17) v = Wlv[k * 17 + c]; }
            else if (n < 64) { int c = n - 48; if (c < 15) v = Wb[k * 15 + c]; }
            else if (n < 784) {
                int r = n - 64, slot = r / 48, c = r % 48;
                if (c < 24) { if (c < 17) v = Wu[k * 255 + slot * 17 + c]; }
                else        { int c2 = c - 24; if (c2 < 17) v = Ww[k * 255 + slot * 17 + c2]; }
            }
        }
        Wht[i3] = f2bf(v);
    } else {
        int j = i - SZ1 - SZ2 - SZ3;
        if (j < 480) {
            b1p[j] = (j < 400) ? b1[j] : 0.f;
        } else if (j < 800) {
            int n = j - 480;
            b2p[n] = (n < 300) ? b2[n] : 0.f;
        } else if (j < 1632) {
            int n = j - 800;
            float v = 0.f;
            if (n < 24)      { if (n < 17) v = bmu[n]; }
            else if (n < 48) { int c = n - 24; if (c < 17) v = blv[c]; }
            else if (n < 64) { int c = n - 48; if (c < 15) v = bb[c]; }
            else if (n < 784) {
                int r = n - 64, slot = r / 48, c = r % 48;
                if (c < 24) { if (c < 17) v = bu[slot * 17 + c]; }
                else        { int c2 = c - 24; if (c2 < 17) v = bw[slot * 17 + c2]; }
            }
            bHp[n] = v;
        }
    }
}

// ---------------------------------------------------------------------------
// gemm_nb: barrier-free, LDS-free GEMM. C' = act(A @ B^T + bias).
//   B-frags read per-lane DIRECTLY from global (weights are L2-resident and
//   shared by all blocks; 16B/lane x 64 = 1KB coalesced per tile).
//   A-frags per-lane from global (CVT_A: f32 x row-major -> bf16 in-reg).
// 256 thr = 4 waves. BM=128, BN=160. Wave (mh=wv>>1, nh=wv&1) owns
// rowtiles [4mh,4mh+4) x ntiles [5nh,5nh+5): acc[4][5]=80 AGPR,
// 9 loads : 20 MFMA per kt. Zero barriers, zero LDS -> fully-unrolled
// load/MFMA dataflow the compiler pipelines deeply (flow-v3 pattern).
// __launch_bounds__(256) PLAIN: unified reg budget 256/wave (2 waves/SIMD),
// the R4-proven no-spill regime. R8's (256,4) forced a 128-reg budget and
// spilled the accumulators in-loop (WRITE 395 MB, 3% MfmaUtil).
// XCD-bijective remap keeps the NX n-blocks of one rowblock on one XCD.
// ---------------------------------------------------------------------------
template<int KITERS, int NX, bool RELU, bool CVT_A>
__global__ __launch_bounds__(256)
void gemm_nb(const ushort_t* __restrict__ At, const float* __restrict__ xf,
             const ushort_t* __restrict__ Bt, const float* __restrict__ bias,
             ushort_t* __restrict__ C, int kTA, int kTC)
{
    const int tid = threadIdx.x;
    const int lane = tid & 63, wv = tid >> 6;
    const int mh = wv >> 1, nh = wv & 1;
    const int q = lane >> 4, l16 = lane & 15;

    // bijective XCD remap (gridDim.x = NX*512; 512 % 8 == 0)
    const int b = blockIdx.x;
    const int xcd = b & 7, idx = b >> 3;
    const int grp = idx / NX;
    const int bx = idx - grp * NX;
    const int by = xcd + grp * 8;
    const int nb0 = bx * 10;
    const int rowblk0 = by * 8;

    f32x4 acc[4][5];
    #pragma unroll
    for (int r = 0; r < 4; ++r)
        #pragma unroll
        for (int c = 0; c < 5; ++c)
            acc[r][c] = (f32x4){0.f, 0.f, 0.f, 0.f};

    #pragma unroll
    for (int kt = 0; kt < KITERS; ++kt) {
        // A-frags: 4 rowtiles, per-lane direct
        bf16x8 a[4];
        #pragma unroll
        for (int r = 0; r < 4; ++r) {
            int rt = rowblk0 + mh * 4 + r;
            if (CVT_A) {
                int row = rt * 16 + l16;
                int k0 = kt * 32 + q * 8;
                uint4 o = {0u, 0u, 0u, 0u};
                if (k0 + 8 <= 376) {
                    const float4* p = reinterpret_cast<const float4*>(
                        xf + (size_t)row * 376 + k0);
                    float4 v0 = p[0], v1 = p[1];
                    o.x = pack2(v0.x, v0.y); o.y = pack2(v0.z, v0.w);
                    o.z = pack2(v1.x, v1.y); o.w = pack2(v1.z, v1.w);
                }
                a[r] = __builtin_bit_cast(bf16x8, o);
            } else {
                a[r] = __builtin_bit_cast(bf16x8, *reinterpret_cast<const uint4*>(
                    At + (((size_t)rt * kTA + kt) << 9) + lane * 8));
            }
        }
        // B-frags: 5 ntiles, per-lane direct from L2-resident weights
        bf16x8 bfr[5];
        #pragma unroll
        for (int c = 0; c < 5; ++c)
            bfr[c] = __builtin_bit_cast(bf16x8, *reinterpret_cast<const uint4*>(
                Bt + (((size_t)(nb0 + nh * 5 + c) * KITERS + kt) << 9) + lane * 8));
        // 20 MFMA
        #pragma unroll
        for (int r = 0; r < 4; ++r)
            #pragma unroll
            for (int c = 0; c < 5; ++c)
                acc[r][c] = __builtin_amdgcn_mfma_f32_16x16x32_bf16(
                    a[r], bfr[c], acc[r][c], 0, 0, 0);
    }

    // ---- epilogue: bias + act -> tiled C; C/D frag: col=l16, row=q*4+reg ----
    #pragma unroll
    for (int r = 0; r < 4; ++r) {
        int rowblk = rowblk0 + mh * 4 + r;
        #pragma unroll
        for (int c = 0; c < 5; ++c) {
            int n = (nb0 + nh * 5 + c) * 16 + l16;
            float bv = bias[n];
            #pragma unroll
            for (int reg = 0; reg < 4; ++reg) {
                float v = acc[r][c][reg] + bv;
                if (RELU) v = fmaxf(v, 0.f);
                int mrow = q * 4 + reg;
                size_t off = (((size_t)rowblk * kTC + (n >> 5)) << 9)
                           + (size_t)(((n >> 3) & 3) * 16 + mrow) * 8 + (n & 7);
                C[off] = f2bf(v);
            }
        }
    }
}

// ---------------------------------------------------------------------------
// gemm_flow2: K3 + planar flow fused, barrier-free GEMM phase.
//   heads(64x800) = h2'(64x320) @ Wh^T + bH. N padded to 832 (52 ntiles) so
//   8 waves split as (wm=wv>>2 -> rowtiles {2wm,2wm+1}, wn=wv&3 -> 13 ntiles).
//   A and B per-lane from global (no LDS, no barriers in the k-loop);
//   acc[2][13]=104 AGPR. Epilogue writes heads to LDS (tiled, cols<800),
//   ONE barrier, then the proven 4-lane flow from LDS.
// LDS = Hd 100 KB only -> 1 block/CU, 8 waves.
// __launch_bounds__(512) plain (unified budget 256/wave, no forced spill).
// ---------------------------------------------------------------------------
__global__ __launch_bounds__(512)
void gemm_flow2(const ushort_t* __restrict__ At, const ushort_t* __restrict__ Bt,
                const float* __restrict__ bias, const float* __restrict__ eps,
                float* __restrict__ out)
{
    __shared__ ushort_t Hd[100 * 512];     // 100 KB: heads for 64 rows, tiled
    const int tid = threadIdx.x;
    const int lane = tid & 63, wv = tid >> 6;
    const int wm = wv >> 2, wn = wv & 3;
    const int q = lane >> 4, l16 = lane & 15;
    const long row0 = (long)blockIdx.x * 64;

    f32x4 acc[2][13];
    #pragma unroll
    for (int r = 0; r < 2; ++r)
        #pragma unroll
        for (int c = 0; c < 13; ++c)
            acc[r][c] = (f32x4){0.f, 0.f, 0.f, 0.f};

    #pragma unroll
    for (int kt = 0; kt < KI3; ++kt) {
        bf16x8 a[2];
        #pragma unroll
        for (int r = 0; r < 2; ++r) {
            size_t rtg = (size_t)blockIdx.x * 4 + wm * 2 + r;
            a[r] = __builtin_bit_cast(bf16x8, *reinterpret_cast<const uint4*>(
                At + ((rtg * KTC2 + kt) << 9) + lane * 8));
        }
        #pragma unroll
        for (int c = 0; c < 13; ++c) {
            bf16x8 bb = __builtin_bit_cast(bf16x8, *reinterpret_cast<const uint4*>(
                Bt + (((size_t)(wn * 13 + c) * KI3 + kt) << 9) + lane * 8));
            acc[0][c] = __builtin_amdgcn_mfma_f32_16x16x32_bf16(a[0], bb, acc[0][c], 0, 0, 0);
            acc[1][c] = __builtin_amdgcn_mfma_f32_16x16x32_bf16(a[1], bb, acc[1][c], 0, 0, 0);
        }
    }

    // ---- epilogue: bias -> heads in LDS (tiled, cols < 800 only) ----
    #pragma unroll
    for (int r = 0; r < 2; ++r) {
        int rts = wm * 2 + r;
        #pragma unroll
        for (int c = 0; c < 13; ++c) {
            int nt = wn * 13 + c;
            if (nt < 50) {                      // wave-uniform per (wn,c)
                int n = nt * 16 + l16;
                float bv = bias[n];
                #pragma unroll
                for (int reg = 0; reg < 4; ++reg) {
                    int r16 = q * 4 + reg;
                    Hd[((rts * KTH + (n >> 5)) << 9) + (((n >> 3) & 3) << 7)
                       + (r16 << 3) + (n & 7)] = f2bf(acc[r][c][reg] + bv);
                }
            }
        }
    }
    __syncthreads();

    // ---- flow phase: threads 0..255 = 64 rows x 4 lanes, heads from LDS ----
    if (tid < 256) {
        const int sub = tid & 3;
        const int row = tid >> 2;
        const ushort_t* hb = &Hd[(((row >> 4) * KTH) << 9) + ((row & 15) << 3)];
        const long grow = row0 + row;

        auto ldg8 = [&](int g, float* dst) {
            uint4 v = *reinterpret_cast<const uint4*>(
                hb + ((g >> 2) << 9) + ((g & 3) << 7));
            unpack8(v, dst);
        };

        float z[8];
        float lp = 0.f;
        {
            float amu[8] = {0,0,0,0,0,0,0,0}, alv[8] = {0,0,0,0,0,0,0,0};
            if (sub < 3) {
                ldg8(sub, amu);
                ldg8(3 + sub, alv);
            }
            float ep[8];
            #pragma unroll
            for (int c = 0; c < 8; ++c) {
                int i = sub * 8 + c;
                ep[c] = (i < 17) ? eps[grow * 17 + i] : 0.f;
            }
            #pragma unroll
            for (int c = 0; c < 8; ++c) {
                float mu = fast_tanh(amu[c]);
                float lv = fast_tanh(alv[c]);
                z[c] = mu + __expf(lv) * ep[c];
                int i = sub * 8 + c;
                lp += (i < 17) ? (-0.5f * ep[c] * ep[c] - lv - 0.918938533f) : 0.f;
            }
        }

        float bv[16];
        ldg8(6, &bv[0]);
        ldg8(7, &bv[8]);

        float ldj = 0.f;
        #pragma unroll
        for (int k = 0; k < 15; ++k) {
            float au[8] = {0,0,0,0,0,0,0,0}, aw[8] = {0,0,0,0,0,0,0,0};
            if (sub < 3) {
                ldg8(8 + 6 * k + sub, au);
                ldg8(11 + 6 * k + sub, aw);
            }
            float uw = 0.f, w2 = 0.f, wz = 0.f;
            #pragma unroll
            for (int c = 0; c < 8; ++c) {
                uw += aw[c] * au[c];
                w2 += aw[c] * aw[c];
                wz += aw[c] * z[c];
            }
            uw += __shfl_xor(uw, 1); uw += __shfl_xor(uw, 2);
            w2 += __shfl_xor(w2, 1); w2 += __shfl_xor(w2, 2);
            wz += __shfl_xor(wz, 1); wz += __shfl_xor(wz, 2);

            float sp = (uw > 15.f) ? uw : __logf(1.f + __expf(uw));
            float m = sp - 1.f;                          // -1 + softplus(w.u)
            float coef = (m - uw) / fmaxf(w2, 1e-20f);
            float t = fast_tanh(wz + bv[k]);
            #pragma unroll
            for (int c = 0; c < 8; ++c)
                z[c] += (au[c] + coef * aw[c]) * t;
            float psi = m * (1.f - t * t);               // psi^T u_hat == m analytically
            ldj += __logf(fmaxf(fabsf(1.f + psi), 1e-30f));
        }

        lp += __shfl_xor(lp, 1); lp += __shfl_xor(lp, 2);
        #pragma unroll
        for (int c = 0; c < 8; ++c) {
            int i = sub * 8 + c;
            if (i < 17) out[grow * 17 + i] = z[c];
        }
        float lpf = lp - ldj;
        if (sub == 0) {
            out[(long)B_ROWS * 17 + grow] = __expf(lpf);
            out[(long)B_ROWS * 18 + grow] = lpf;
        }
    }
}

// ---------------------------------------------------------------------------
extern "C" void kernel_launch(void* const* d_in, const int* in_sizes, int n_in,
                              void* d_out, int out_size, void* d_ws, size_t ws_size,
                              hipStream_t stream)
{
    const float* x   = (const float*)d_in[0];
    const float* eps = (const float*)d_in[1];
    float* out = (float*)d_out;

    // ws layout (ushort units): [h2'][h1'][weights + biases]
    ushort_t* ws = (ushort_t*)d_ws;
    ushort_t* R_h2 = ws;
    ushort_t* R_h1 = ws + H2_US;
    ushort_t* W1t = ws + H2_US + H1_US;
    ushort_t* W2t = W1t + SZ1;
    ushort_t* Wht = W2t + SZ2;
    float* b1p = (float*)(Wht + SZ3);
    float* b2p = b1p + 480;
    float* bHp = b2p + 320;

    const int packN = SZ1 + SZ2 + SZ3 + 1632;
    pack_kernel<<<(packN + 255) / 256, 256, 0, stream>>>(
        (const float*)d_in[2],  (const float*)d_in[4],
        (const float*)d_in[6],  (const float*)d_in[8],
        (const float*)d_in[10], (const float*)d_in[12], (const float*)d_in[14],
        (const float*)d_in[3],  (const float*)d_in[5],
        (const float*)d_in[7],  (const float*)d_in[9],
        (const float*)d_in[11], (const float*)d_in[13], (const float*)d_in[15],
        W1t, W2t, Wht, b1p, b2p, bHp);

    // K1: h1' = relu(x @ W1^T + b1), cvt fused.  M=65536 K=384 N=480
    gemm_nb<KT1, 3, true, true><<<3 * 512, 256, 0, stream>>>(
        nullptr, x, W1t, b1p, R_h1, 0, KTC1);
    // K2: h2' = relu(h1' @ W2^T + b2).           M=65536 K=416 N=320
    gemm_nb<KI2, 2, true, false><<<2 * 512, 256, 0, stream>>>(
        R_h1, nullptr, W2t, b2p, R_h2, KTC1, KTC2);
    // K3+K4 fused: heads (LDS-resident) + planar flow + log-prob
    gemm_flow2<<<B_ROWS / 64, 512, 0, stream>>>(R_h2, Wht, bHp, eps, out);
}

// Round 10
// 330.624 us; speedup vs baseline: 2.0616x; 1.2757x over previous
//
#include <hip/hip_runtime.h>

typedef unsigned short ushort_t;
typedef unsigned int uint_t;
typedef __bf16 bf16x8 __attribute__((ext_vector_type(8)));
typedef float f32x4 __attribute__((ext_vector_type(4)));

#define B_ROWS 65536

// Tile geometry: one MFMA tile = 16 rows x 32 k of bf16 = 1024 B = 512 ushorts.
// Unit l (0..63) within a tile <-> (row = l&15, k = (l>>4)*8 .. +8).
#define KT1 12    // K1 k-iters  (K 376 -> 384)
#define NT1 30    // K1 n-tiles  (N 400 -> 480)
#define KTC1 15   // h1' k-tiles (480/32)
#define KI2 13    // K2 k-iters  (K 400 -> 416; h1' cols 400..480 are exact 0)
#define NT2 20    // K2 n-tiles  (N 320)
#define KTC2 10   // h2' k-tiles (320/32)
#define KI3 10    // K3 k-iters  (320/32)
#define NT3 50    // K3 n-tiles  (N 800: aligned head layout)
#define KTH 25    // heads row-stride in ktiles (800/32)

// Aligned head layout (all slots on 8-col boundaries; pads are exact zeros):
//  [0:24)  mu (17 real)   groups 0..2
//  [24:48) lv (17 real)   groups 3..5
//  [48:64) b  (15 real)   groups 6..7
//  [64+48k : +24)  u_k (17 real)  groups 8+6k .. +2
//  [64+48k+24 : +48) w_k (17 real) groups 11+6k .. +2

#define SZ1 (NT1 * KT1 * 512)
#define SZ2 (NT2 * KI2 * 512)
#define SZ3 (NT3 * KI3 * 512)

// workspace (ushort units): [h2'][h1' -> overlaid by heads][weights]
#define H2_US    ((size_t)4096 * KTC2 * 512)
#define HEADS_US ((size_t)4096 * KTH * 512)

__device__ inline ushort_t f2bf(float f) {
    uint_t u = __float_as_uint(f);
    return (ushort_t)((u + 0x7FFFu + ((u >> 16) & 1u)) >> 16);
}
__device__ inline uint_t pack2(float a, float b) {
    return (uint_t)f2bf(a) | ((uint_t)f2bf(b) << 16);
}
__device__ inline float fast_tanh(float x) {
    float e = __expf(2.f * x);
    return 1.f - 2.f / (e + 1.f);
}
// async global->LDS, 16 B per lane; LDS dest = wave-uniform base + lane*16
__device__ inline void gl2lds16(const ushort_t* g, ushort_t* l) {
    __builtin_amdgcn_global_load_lds(
        (const __attribute__((address_space(1))) uint_t*)g,
        (__attribute__((address_space(3))) uint_t*)l, 16, 0, 0);
}
__device__ inline void unpack8(uint4 v, float* dst) {
    uint_t q[4] = {v.x, v.y, v.z, v.w};
    #pragma unroll
    for (int m = 0; m < 4; ++m) {
        dst[2 * m]     = __uint_as_float(q[m] << 16);          // low bf16
        dst[2 * m + 1] = __uint_as_float(q[m] & 0xFFFF0000u);  // high bf16
    }
}

// ---------------------------------------------------------------------------
// pack_kernel: fp32 weights -> MFMA-tile-order bf16 + zero-padded fp32 biases.
// ---------------------------------------------------------------------------
__global__ void pack_kernel(const float* __restrict__ W1, const float* __restrict__ W2,
                            const float* __restrict__ Wmu, const float* __restrict__ Wlv,
                            const float* __restrict__ Wu, const float* __restrict__ Ww,
                            const float* __restrict__ Wb,
                            const float* __restrict__ b1, const float* __restrict__ b2,
                            const float* __restrict__ bmu, const float* __restrict__ blv,
                            const float* __restrict__ bu, const float* __restrict__ bw,
                            const float* __restrict__ bb,
                            ushort_t* __restrict__ W1t, ushort_t* __restrict__ W2t,
                            ushort_t* __restrict__ Wht,
                            float* __restrict__ b1p, float* __restrict__ b2p,
                            float* __restrict__ bHp)
{
    int i = blockIdx.x * 256 + threadIdx.x;
    if (i < SZ1) {
        int t = i >> 9, pos = i & 511;
        int l = pos >> 3, j = pos & 7;
        int n = (t / KT1) * 16 + (l & 15);
        int k = (t % KT1) * 32 + (l >> 4) * 8 + j;
        W1t[i] = (n < 400 && k < 376) ? f2bf(W1[k * 400 + n]) : (ushort_t)0;
    } else if (i < SZ1 + SZ2) {
        int i2 = i - SZ1;
        int t = i2 >> 9, pos = i2 & 511;
        int l = pos >> 3, j = pos & 7;
        int n = (t / KI2) * 16 + (l & 15);
        int k = (t % KI2) * 32 + (l >> 4) * 8 + j;
        W2t[i2] = (n < 300 && k < 400) ? f2bf(W2[k * 300 + n]) : (ushort_t)0;
    } else if (i < SZ1 + SZ2 + SZ3) {
        int i3 = i - SZ1 - SZ2;
        int t = i3 >> 9, pos = i3 & 511;
        int l = pos >> 3, j = pos & 7;
        int n = (t / KI3) * 16 + (l & 15);
        int k = (t % KI3) * 32 + (l >> 4) * 8 + j;
        float v = 0.f;
        if (k < 300) {
            if (n < 24)      { if (n < 17) v = Wmu[k * 17 + n]; }
            else if (n < 48) { int c = n - 24; if (c < 17) v = Wlv[k * 17 + c]; }
            else if (n < 64) { int c = n - 48; if (c < 15) v = Wb[k * 15 + c]; }
            else if (n < 784) {
                int r = n - 64, slot = r / 48, c = r % 48;
                if (c < 24) { if (c < 17) v = Wu[k * 255 + slot * 17 + c]; }
                else        { int c2 = c - 24; if (c2 < 17) v = Ww[k * 255 + slot * 17 + c2]; }
            }
        }
        Wht[i3] = f2bf(v);
    } else {
        int j = i - SZ1 - SZ2 - SZ3;
        if (j < 480) {
            b1p[j] = (j < 400) ? b1[j] : 0.f;
        } else if (j < 800) {
            int n = j - 480;
            b2p[n] = (n < 300) ? b2[n] : 0.f;
        } else if (j < 1600) {
            int n = j - 800;
            float v = 0.f;
            if (n < 24)      { if (n < 17) v = bmu[n]; }
            else if (n < 48) { int c = n - 24; if (c < 17) v = blv[c]; }
            else if (n < 64) { int c = n - 48; if (c < 15) v = bb[c]; }
            else if (n < 784) {
                int r = n - 64, slot = r / 48, c = r % 48;
                if (c < 24) { if (c < 17) v = bu[slot * 17 + c]; }
                else        { int c2 = c - 24; if (c2 < 17) v = bw[slot * 17 + c2]; }
            }
            bHp[n] = v;
        }
    }
}

// ---------------------------------------------------------------------------
// gemm_t3: R4's gemm_db + T4 deep pipeline (counted vmcnt, raw s_barrier).
//   4-deep LDS ring; stage(kt+2) issued each iteration; ONE raw barrier per
//   iteration; loads stay in flight ACROSS barriers (never vmcnt(0) mid-loop).
//   Race-freedom: write targets (kt+2)%4 / (kt+3)%4 never alias read target
//   kt%4 within one barrier window; batch(kt) completion at barrier_kt is
//   guaranteed by in-order vmcnt semantics:
//    - non-CVT: explicit vmcnt(8)/(4)/(0)  (min 4 gl2lds per wave per batch;
//      waiting to <=8 drains everything older than the last 2 batches).
//    - CVT_A (K1): A loaded to regs (ra[2], 2 iters ahead), ds_written 1 iter
//      ahead; the compiler's auto reg-wait for ra drains batch(kt) in-order;
//      explicit wait is lgkmcnt(0) (ds_writes visible before barrier).
//   sched_barrier(0) fences around the asm (rule: compiler may otherwise
//   hoist ds_reads past inline-asm waits).
// BM=128 (8 rowtiles), BN=160 (10 ntiles), BK=32; 256 thr = 4 waves.
// LDS 4*(8+10) KB = 72 KB -> 2 blocks/CU.
// XCD-bijective remap keeps the NX n-blocks of one rowblock on one XCD.
// ---------------------------------------------------------------------------
template<int KITERS, int NX, bool RELU, bool CVT_A>
__global__ __launch_bounds__(256)
void gemm_t3(const ushort_t* __restrict__ At, const float* __restrict__ xf,
             const ushort_t* __restrict__ Bt, const float* __restrict__ bias,
             ushort_t* __restrict__ C, int kTA, int kTC)
{
    __shared__ ushort_t As[4][8 * 512];
    __shared__ ushort_t Bs[4][10 * 512];
    const int tid = threadIdx.x;
    const int lane = tid & 63, wv = tid >> 6;
    const int q = lane >> 4, l16 = lane & 15;

    // bijective XCD remap (gridDim.x = NX*512; 512 % 8 == 0)
    const int b = blockIdx.x;
    const int xcd = b & 7, idx = b >> 3;
    const int grp = idx / NX;
    const int bx = idx - grp * NX;
    const int by = xcd + grp * 8;
    const int nb0 = bx * 10;
    const int rowblk0 = by * 8;

    // CVT staging geometry (thread -> tiles ct, ct+4 at unit cl)
    const int ct = wv;
    const int cl = lane;
    const int crow0 = (rowblk0 + ct) * 16 + (cl & 15);
    const int crow1 = (rowblk0 + ct + 4) * 16 + (cl & 15);
    const int ckoff = (cl >> 4) * 8;

    float4 ra[2][4];   // CVT: two in-flight A batches (2 rows x 2 float4 each)

    auto stage = [&](int j, int buf) {
        if (CVT_A) {
            int k0 = j * 32 + ckoff;
            #pragma unroll
            for (int r = 0; r < 2; ++r) {
                int row = r ? crow1 : crow0;
                float4 lo = {0.f, 0.f, 0.f, 0.f}, hi = {0.f, 0.f, 0.f, 0.f};
                if (k0 + 8 <= 376) {
                    const float4* p = reinterpret_cast<const float4*>(
                        xf + (size_t)row * 376 + k0);
                    lo = p[0]; hi = p[1];
                }
                ra[j & 1][2 * r] = lo;
                ra[j & 1][2 * r + 1] = hi;
            }
        } else {
            #pragma unroll
            for (int i = 0; i < 2; ++i) {
                int t = wv * 2 + i;
                gl2lds16(At + (((size_t)(rowblk0 + t) * kTA + j) << 9) + lane * 8,
                         &As[buf][t << 9]);
            }
        }
        #pragma unroll
        for (int t2 = 0; t2 < 3; ++t2) {
            int t = wv + t2 * 4;
            if (t < 10)
                gl2lds16(Bt + (((size_t)(nb0 + t) * KITERS + j) << 9) + lane * 8,
                         &Bs[buf][t << 9]);
        }
    };
    auto dswriteA = [&](int j, int buf) {   // CVT only; auto reg-wait drains older VMEM
        float4 lo0 = ra[j & 1][0], hi0 = ra[j & 1][1];
        uint4 o0;
        o0.x = pack2(lo0.x, lo0.y); o0.y = pack2(lo0.z, lo0.w);
        o0.z = pack2(hi0.x, hi0.y); o0.w = pack2(hi0.z, hi0.w);
        *reinterpret_cast<uint4*>(&As[buf][(ct << 9) + (cl << 3)]) = o0;
        float4 lo1 = ra[j & 1][2], hi1 = ra[j & 1][3];
        uint4 o1;
        o1.x = pack2(lo1.x, lo1.y); o1.y = pack2(lo1.z, lo1.w);
        o1.z = pack2(hi1.x, hi1.y); o1.w = pack2(hi1.z, hi1.w);
        *reinterpret_cast<uint4*>(&As[buf][((ct + 4) << 9) + (cl << 3)]) = o1;
    };

    f32x4 acc[2][10];
    #pragma unroll
    for (int r = 0; r < 2; ++r)
        #pragma unroll
        for (int c = 0; c < 10; ++c)
            acc[r][c] = (f32x4){0.f, 0.f, 0.f, 0.f};

    // ---- prologue: two batches in flight; A(0) ds_written ----
    stage(0, 0);
    stage(1, 1);
    if (CVT_A) dswriteA(0, 0);

    // ---- main loop: one raw barrier per kt, counted waits ----
    #pragma unroll
    for (int kt = 0; kt < KITERS; ++kt) {
        if (kt + 2 < KITERS) stage(kt + 2, (kt + 2) & 3);
        if (CVT_A && kt + 1 < KITERS) dswriteA(kt + 1, (kt + 1) & 3);

        if (CVT_A) {
            if (kt == KITERS - 1)
                asm volatile("s_waitcnt vmcnt(0) lgkmcnt(0)" ::: "memory");
            else
                asm volatile("s_waitcnt lgkmcnt(0)" ::: "memory");
        } else {
            if (kt + 2 < KITERS)
                asm volatile("s_waitcnt vmcnt(8)" ::: "memory");
            else if (kt + 1 < KITERS)
                asm volatile("s_waitcnt vmcnt(4)" ::: "memory");
            else
                asm volatile("s_waitcnt vmcnt(0)" ::: "memory");
        }
        __builtin_amdgcn_sched_barrier(0);
        __builtin_amdgcn_s_barrier();
        __builtin_amdgcn_sched_barrier(0);

        const int p = kt & 3;
        bf16x8 a0 = __builtin_bit_cast(bf16x8,
            *reinterpret_cast<const uint4*>(&As[p][((wv * 2 + 0) << 9) + lane * 8]));
        bf16x8 a1 = __builtin_bit_cast(bf16x8,
            *reinterpret_cast<const uint4*>(&As[p][((wv * 2 + 1) << 9) + lane * 8]));
        #pragma unroll
        for (int c = 0; c < 10; ++c) {
            bf16x8 bb = __builtin_bit_cast(bf16x8,
                *reinterpret_cast<const uint4*>(&Bs[p][(c << 9) + lane * 8]));
            acc[0][c] = __builtin_amdgcn_mfma_f32_16x16x32_bf16(a0, bb, acc[0][c], 0, 0, 0);
            acc[1][c] = __builtin_amdgcn_mfma_f32_16x16x32_bf16(a1, bb, acc[1][c], 0, 0, 0);
        }
    }

    // ---- epilogue: bias + act -> tiled C; C/D frag: col=l16, row=q*4+reg ----
    #pragma unroll
    for (int r = 0; r < 2; ++r) {
        int rowblk = rowblk0 + wv * 2 + r;
        #pragma unroll
        for (int c = 0; c < 10; ++c) {
            int n = (nb0 + c) * 16 + l16;
            float bv = bias[n];
            #pragma unroll
            for (int reg = 0; reg < 4; ++reg) {
                float v = acc[r][c][reg] + bv;
                if (RELU) v = fmaxf(v, 0.f);
                int mrow = q * 4 + reg;
                size_t off = (((size_t)rowblk * kTC + (n >> 5)) << 9)
                           + (size_t)(((n >> 3) & 3) * 16 + mrow) * 8 + (n & 7);
                C[off] = f2bf(v);
            }
        }
    }
}

// ---------------------------------------------------------------------------
// flow_kernel v3: 4 lanes per row (lane sub owns head cols [8*sub, 8*sub+8)).
// Aligned 48-col u/w slots -> one uint4 per lane per vector, fully coalesced.
// Dots reduced across the 4-lane group via shfl_xor(1,2). No LDS, no spills.
// ---------------------------------------------------------------------------
__device__ inline void ld_group8(const ushort_t* hb, int g, float* dst) {
    uint4 v = *reinterpret_cast<const uint4*>(hb + ((g >> 2) << 9) + ((g & 3) << 7));
    unpack8(v, dst);
}

__global__ __launch_bounds__(256, 4)
void flow_kernel(const ushort_t* __restrict__ heads, const float* __restrict__ eps,
                 float* __restrict__ out, int Btot)
{
    const int tid = threadIdx.x;
    const int sub = tid & 3;
    const long row = (long)blockIdx.x * 64 + (tid >> 2);
    const ushort_t* hb = heads + (((size_t)(row >> 4) * KTH) << 9)
                               + (size_t)((row & 15) << 3);

    float z[8];
    float lp = 0.f;
    {
        float amu[8] = {0,0,0,0,0,0,0,0}, alv[8] = {0,0,0,0,0,0,0,0};
        if (sub < 3) {
            ld_group8(hb, sub, amu);
            ld_group8(hb, 3 + sub, alv);
        }
        float ep[8];
        #pragma unroll
        for (int c = 0; c < 8; ++c) {
            int i = sub * 8 + c;
            ep[c] = (i < 17) ? eps[row * 17 + i] : 0.f;
        }
        #pragma unroll
        for (int c = 0; c < 8; ++c) {
            float mu = fast_tanh(amu[c]);
            float lv = fast_tanh(alv[c]);
            z[c] = mu + __expf(lv) * ep[c];
            int i = sub * 8 + c;
            lp += (i < 17) ? (-0.5f * ep[c] * ep[c] - lv - 0.918938533f) : 0.f;
        }
    }

    float bv[16];
    ld_group8(hb, 6, &bv[0]);
    ld_group8(hb, 7, &bv[8]);

    float ldj = 0.f;
    #pragma unroll
    for (int k = 0; k < 15; ++k) {
        float au[8] = {0,0,0,0,0,0,0,0}, aw[8] = {0,0,0,0,0,0,0,0};
        if (sub < 3) {
            ld_group8(hb, 8 + 6 * k + sub, au);
            ld_group8(hb, 11 + 6 * k + sub, aw);
        }
        float uw = 0.f, w2 = 0.f, wz = 0.f;
        #pragma unroll
        for (int c = 0; c < 8; ++c) {
            uw += aw[c] * au[c];
            w2 += aw[c] * aw[c];
            wz += aw[c] * z[c];
        }
        uw += __shfl_xor(uw, 1); uw += __shfl_xor(uw, 2);
        w2 += __shfl_xor(w2, 1); w2 += __shfl_xor(w2, 2);
        wz += __shfl_xor(wz, 1); wz += __shfl_xor(wz, 2);

        float sp = (uw > 15.f) ? uw : __logf(1.f + __expf(uw));
        float m = sp - 1.f;                          // -1 + softplus(w.u)
        float coef = (m - uw) / fmaxf(w2, 1e-20f);
        float t = fast_tanh(wz + bv[k]);
        #pragma unroll
        for (int c = 0; c < 8; ++c)
            z[c] += (au[c] + coef * aw[c]) * t;
        float psi = m * (1.f - t * t);               // psi^T u_hat == m analytically
        ldj += __logf(fmaxf(fabsf(1.f + psi), 1e-30f));
    }

    lp += __shfl_xor(lp, 1); lp += __shfl_xor(lp, 2);
    #pragma unroll
    for (int c = 0; c < 8; ++c) {
        int i = sub * 8 + c;
        if (i < 17) out[row * 17 + i] = z[c];
    }
    float lpf = lp - ldj;
    if (sub == 0) {
        out[(long)Btot * 17 + row] = __expf(lpf);
        out[(long)Btot * 18 + row] = lpf;
    }
}

// ---------------------------------------------------------------------------
extern "C" void kernel_launch(void* const* d_in, const int* in_sizes, int n_in,
                              void* d_out, int out_size, void* d_ws, size_t ws_size,
                              hipStream_t stream)
{
    const float* x   = (const float*)d_in[0];
    const float* eps = (const float*)d_in[1];
    float* out = (float*)d_out;

    // ws layout (ushort units):
    //  [0, H2_US)                 h2' tiled (stride KTC2)
    //  [H2_US, H2_US+HEADS_US)    h1' tiled (stride KTC1) then heads tiled
    //                             (stride KTH) -- h1' dead by K3
    //  weights after + biases
    ushort_t* ws = (ushort_t*)d_ws;
    ushort_t* R_h2    = ws;
    ushort_t* R_h1    = ws + H2_US;
    ushort_t* R_heads = ws + H2_US;        // overlays h1'
    ushort_t* W1t = ws + H2_US + HEADS_US;
    ushort_t* W2t = W1t + SZ1;
    ushort_t* Wht = W2t + SZ2;
    float* b1p = (float*)(Wht + SZ3);
    float* b2p = b1p + 480;
    float* bHp = b2p + 320;

    const int packN = SZ1 + SZ2 + SZ3 + 1600;
    pack_kernel<<<(packN + 255) / 256, 256, 0, stream>>>(
        (const float*)d_in[2],  (const float*)d_in[4],
        (const float*)d_in[6],  (const float*)d_in[8],
        (const float*)d_in[10], (const float*)d_in[12], (const float*)d_in[14],
        (const float*)d_in[3],  (const float*)d_in[5],
        (const float*)d_in[7],  (const float*)d_in[9],
        (const float*)d_in[11], (const float*)d_in[13], (const float*)d_in[15],
        W1t, W2t, Wht, b1p, b2p, bHp);

    // K1: h1' = relu(x @ W1^T + b1), cvt fused.  M=65536 K=384 N=480
    gemm_t3<KT1, 3, true, true><<<3 * 512, 256, 0, stream>>>(
        nullptr, x, W1t, b1p, R_h1, 0, KTC1);
    // K2: h2' = relu(h1' @ W2^T + b2).           M=65536 K=416 N=320
    gemm_t3<KI2, 2, true, false><<<2 * 512, 256, 0, stream>>>(
        R_h1, nullptr, W2t, b2p, R_h2, KTC1, KTC2);
    // K3: heads = h2' @ Wh^T + bH.               M=65536 K=320 N=800
    gemm_t3<KI3, 5, false, false><<<5 * 512, 256, 0, stream>>>(
        R_h2, nullptr, Wht, bHp, R_heads, KTC2, KTH);
    // K4: planar flow + log-prob
    flow_kernel<<<B_ROWS / 64, 256, 0, stream>>>(R_heads, eps, out, B_ROWS);
}